// Round 3
// baseline (2684.838 us; speedup 1.0000x reference)
//
#include <hip/hip_runtime.h>

typedef __attribute__((ext_vector_type(8))) short bf16x8;
typedef __attribute__((ext_vector_type(4))) float f32x4;
typedef unsigned short u16;

// ---------- helpers ----------
__device__ inline u16 f2b(float f) {
  union { float f; unsigned u; } x; x.f = f;
  unsigned r = x.u + 0x7FFFu + ((x.u >> 16) & 1u);
  return (u16)(r >> 16);
}
__device__ inline float b2f(u16 s) {
  union { unsigned u; float f; } x; x.u = ((unsigned)s) << 16;
  return x.f;
}
__device__ inline float gelu_f(float v) {
  return 0.5f * v * (1.0f + erff(v * 0.70710678118654752f));
}
__device__ inline void gll16(const void* g, void* lds) {
  __builtin_amdgcn_global_load_lds((const __attribute__((address_space(1))) void*)g,
                                   (__attribute__((address_space(3))) void*)lds,
                                   16, 0, 0);
}

// ---------- weight convert fp32 -> bf16 ----------
__global__ __launch_bounds__(256) void cvt_w(const float* __restrict__ s,
                                             u16* __restrict__ d, int n4) {
  int i = blockIdx.x * 256 + threadIdx.x;
  if (i < n4) {
    float4 v = ((const float4*)s)[i];
    ushort4 o; o.x = f2b(v.x); o.y = f2b(v.y); o.z = f2b(v.z); o.w = f2b(v.w);
    ((ushort4*)d)[i] = o;
  }
}

__global__ __launch_bounds__(256) void cat_bias(const float* __restrict__ a,
                                                const float* __restrict__ b,
                                                float* __restrict__ o) {
  int i = blockIdx.x * 256 + threadIdx.x;
  if (i < 1024) { o[i] = a[i]; o[1024 + i] = b[i]; }
}

// ---------- fused x->bf16 convert + 2x2x2 mean pool ----------
__global__ __launch_bounds__(256) void pool_cvt(const float* __restrict__ xg,
                                                u16* __restrict__ Xb,
                                                u16* __restrict__ Qp) {
  int qr = blockIdx.x;
  int wgi = qr & 15;
  int hgi = (qr >> 4) % 20;
  int dgi = qr / 320;
  int c = threadIdx.x * 4;
  float sx = 0.f, sy = 0.f, sz = 0.f, sw = 0.f;
#pragma unroll
  for (int j = 0; j < 8; ++j) {
    int tr = ((2 * dgi + (j >> 2)) * 40 + (2 * hgi + ((j >> 1) & 1))) * 32 +
             (2 * wgi + (j & 1));
    long off = (long)tr * 1024 + c;
    float4 v = *(const float4*)&xg[off];
    ushort4 o; o.x = f2b(v.x); o.y = f2b(v.y); o.z = f2b(v.z); o.w = f2b(v.w);
    *(ushort4*)&Xb[off] = o;
    sx += v.x; sy += v.y; sz += v.z; sw += v.w;
  }
  ushort4 o;
  o.x = f2b(sx * 0.125f); o.y = f2b(sy * 0.125f);
  o.z = f2b(sz * 0.125f); o.w = f2b(sw * 0.125f);
  *(ushort4*)&Qp[(long)qr * 1024 + c] = o;
}

// ---------- in-place LayerNorm over rows of 1024 bf16 ----------
__global__ __launch_bounds__(256) void ln_ip(u16* __restrict__ X,
                                             const float* __restrict__ w,
                                             const float* __restrict__ b) {
  long row = blockIdx.x;
  int c = threadIdx.x * 4;
  ushort4 v = *(const ushort4*)&X[row * 1024 + c];
  float f0 = b2f(v.x), f1 = b2f(v.y), f2 = b2f(v.z), f3 = b2f(v.w);
  float s = f0 + f1 + f2 + f3;
  float q = f0 * f0 + f1 * f1 + f2 * f2 + f3 * f3;
#pragma unroll
  for (int off = 32; off >= 1; off >>= 1) {
    s += __shfl_xor(s, off);
    q += __shfl_xor(q, off);
  }
  __shared__ float red[8];
  int wv = threadIdx.x >> 6, ln = threadIdx.x & 63;
  if (ln == 0) { red[wv] = s; red[4 + wv] = q; }
  __syncthreads();
  s = red[0] + red[1] + red[2] + red[3];
  q = red[4] + red[5] + red[6] + red[7];
  float mean = s * (1.f / 1024.f);
  float var = q * (1.f / 1024.f) - mean * mean;
  float rs = rsqrtf(var + 1e-6f);
  float4 wv4 = *(const float4*)&w[c];
  float4 bv4 = *(const float4*)&b[c];
  ushort4 o;
  o.x = f2b((f0 - mean) * rs * wv4.x + bv4.x);
  o.y = f2b((f1 - mean) * rs * wv4.y + bv4.y);
  o.z = f2b((f2 - mean) * rs * wv4.z + bv4.z);
  o.w = f2b((f3 - mean) * rs * wv4.w + bv4.w);
  *(ushort4*)&X[row * 1024 + c] = o;
}

// ---------- 256x256 8-phase GEMM: C[M,N] = A[M,K(lda)] @ B[N,K]^T ----------
// EPI: 0 bias->bf16 ; 1 bias+gelu->bf16 ; 2 bias->fp32 ; 3 nobias->bf16
// 512 thr = 8 waves (2M x 4N); BK=64; LDS = 4 A-half-slots + 4 B-half-slots
// (half = 128 rows x 64 cols bf16 = 16KB). Counted vmcnt(6) once per K-tile.
#define HALF 8192
#define MFMA16(a, b, c) __builtin_amdgcn_mfma_f32_16x16x32_bf16((a), (b), (c), 0, 0, 0)

template <int EPI>
__global__ __launch_bounds__(512, 2) void gemm256(const u16* __restrict__ A,
                                                  const u16* __restrict__ B,
                                                  const float* __restrict__ bias,
                                                  float* __restrict__ Cf,
                                                  u16* __restrict__ Cb,
                                                  int M, int N, int K, int lda,
                                                  int nbx, int nby) {
  extern __shared__ u16 lds[];
  u16* ASm = lds;
  u16* BSm = lds + 4 * HALF;
  const int tid = threadIdx.x;
  const int l = tid & 63, w = tid >> 6;
  const int wr = w >> 2, wc = w & 3;
  const int lr = l & 15, kg = l >> 4;
  const int e7 = l & 7;

  // XCD-aware swizzle
  int L = blockIdx.x, bx, by;
  if ((nbx & 7) == 0) {
    int xcd = L & 7, j = L >> 3, ppx = nbx >> 3;
    int pj = j / nby;
    bx = xcd * ppx + pj;
    by = j - pj * nby;
  } else {
    bx = L % nbx;
    by = L / nbx;
  }
  const int bm = bx * 256, bn = by * 256;

  // staging geometry: thread handles chunks c0, c1 of each 1024-chunk half
  const int c0 = w * 64 + l, c1 = 512 + c0;
  const int r0 = c0 >> 3, cs0 = (c0 & 7) ^ (r0 & 7);   // inverse-swizzled src chunk
  const int r1 = c1 >> 3, cs1 = (c1 & 7) ^ (r1 & 7);
  const u16* Ab = A + (long)bm * lda;
  const u16* Bb = B + (long)bn * K;
  int a0r0 = min(bm + r0, M - 1) - bm;
  int a0r1 = min(bm + r1, M - 1) - bm;
  int a1r0 = min(bm + 128 + r0, M - 1) - bm;
  int a1r1 = min(bm + 128 + r1, M - 1) - bm;
  const int oA00 = a0r0 * lda + cs0 * 8, oA01 = a0r1 * lda + cs1 * 8;
  const int oA10 = a1r0 * lda + cs0 * 8, oA11 = a1r1 * lda + cs1 * 8;
  const int oB00 = r0 * K + cs0 * 8, oB01 = r1 * K + cs1 * 8;
  const int oB10 = (128 + r0) * K + cs0 * 8, oB11 = (128 + r1) * K + cs1 * 8;
  const int d0 = c0 * 8, d1 = c1 * 8;

  // swizzled ds_read chunk offsets (elems) for ks=0,1
  const int sw0 = ((kg) ^ e7) * 8;
  const int sw1 = ((4 + kg) ^ e7) * 8;

  f32x4 acc[8][4] = {};
  bf16x8 af[4][2], bf[2][2][2];
  const int nt = K / 64;

#define STG_A(slot, o0_, o1_, ko) do { \
    gll16(Ab + (o0_) + (ko), ASm + (slot) * HALF + d0); \
    gll16(Ab + (o1_) + (ko), ASm + (slot) * HALF + d1); } while (0)
#define STG_B(slot, o0_, o1_, ko) do { \
    gll16(Bb + (o0_) + (ko), BSm + (slot) * HALF + d0); \
    gll16(Bb + (o1_) + (ko), BSm + (slot) * HALF + d1); } while (0)

  // prologue: tile0 full into parity-0 slots; tile1 Ah0/Bh0/Bh1 into parity-1
  STG_A(0, oA00, oA01, 0); STG_A(1, oA10, oA11, 0);
  STG_B(0, oB00, oB01, 0); STG_B(1, oB10, oB11, 0);
  STG_A(2, oA00, oA01, 64); STG_B(2, oB00, oB01, 64); STG_B(3, oB10, oB11, 64);
  asm volatile("s_waitcnt vmcnt(6)" ::: "memory");
  __builtin_amdgcn_s_barrier();

  const int rbA = wr * 64 + lr;
  const int rbB = (wc & 1) * 64 + lr;

  for (int t = 0; t < nt; ++t) {
    const int p = t & 1, qp = p ^ 1;
    const int kn1 = (t + 1 < nt ? t + 1 : nt - 1) * 64;
    const int kn2 = (t + 2 < nt ? t + 2 : nt - 1) * 64;
    const u16* sa0 = ASm + (p * 2 + 0) * HALF;
    const u16* sa1 = ASm + (p * 2 + 1) * HALF;
    const u16* sb = BSm + (p * 2 + (wc >> 1)) * HALF;

    // ---- phase 1: quadrant (mh0,nh0); stage A-h1(t+1)
#pragma unroll
    for (int mq = 0; mq < 4; ++mq) {
      af[mq][0] = *(const bf16x8*)&sa0[(rbA + mq * 16) * 64 + sw0];
      af[mq][1] = *(const bf16x8*)&sa0[(rbA + mq * 16) * 64 + sw1];
    }
#pragma unroll
    for (int nn = 0; nn < 2; ++nn) {
      bf[0][nn][0] = *(const bf16x8*)&sb[(rbB + nn * 16) * 64 + sw0];
      bf[0][nn][1] = *(const bf16x8*)&sb[(rbB + nn * 16) * 64 + sw1];
    }
    STG_A(qp * 2 + 1, oA10, oA11, kn1);
    __builtin_amdgcn_s_barrier();
    __builtin_amdgcn_s_setprio(1);
#pragma unroll
    for (int mq = 0; mq < 4; ++mq)
#pragma unroll
      for (int nn = 0; nn < 2; ++nn) {
        acc[mq][nn] = MFMA16(af[mq][0], bf[0][nn][0], acc[mq][nn]);
        acc[mq][nn] = MFMA16(af[mq][1], bf[0][nn][1], acc[mq][nn]);
      }
    __builtin_amdgcn_s_setprio(0);
    __builtin_amdgcn_s_barrier();

    // ---- phase 2: (mh0,nh1); stage A-h0(t+2)
#pragma unroll
    for (int nn = 0; nn < 2; ++nn) {
      bf[1][nn][0] = *(const bf16x8*)&sb[(rbB + (2 + nn) * 16) * 64 + sw0];
      bf[1][nn][1] = *(const bf16x8*)&sb[(rbB + (2 + nn) * 16) * 64 + sw1];
    }
    STG_A(p * 2 + 0, oA00, oA01, kn2);
    __builtin_amdgcn_s_barrier();
    __builtin_amdgcn_s_setprio(1);
#pragma unroll
    for (int mq = 0; mq < 4; ++mq)
#pragma unroll
      for (int nn = 0; nn < 2; ++nn) {
        acc[mq][2 + nn] = MFMA16(af[mq][0], bf[1][nn][0], acc[mq][2 + nn]);
        acc[mq][2 + nn] = MFMA16(af[mq][1], bf[1][nn][1], acc[mq][2 + nn]);
      }
    __builtin_amdgcn_s_setprio(0);
    __builtin_amdgcn_s_barrier();

    // ---- phase 3: (mh1,nh0); stage B-h0(t+2)
#pragma unroll
    for (int mq = 0; mq < 4; ++mq) {
      af[mq][0] = *(const bf16x8*)&sa1[(rbA + mq * 16) * 64 + sw0];
      af[mq][1] = *(const bf16x8*)&sa1[(rbA + mq * 16) * 64 + sw1];
    }
    STG_B(p * 2 + 0, oB00, oB01, kn2);
    __builtin_amdgcn_s_barrier();
    __builtin_amdgcn_s_setprio(1);
#pragma unroll
    for (int mq = 0; mq < 4; ++mq)
#pragma unroll
      for (int nn = 0; nn < 2; ++nn) {
        acc[4 + mq][nn] = MFMA16(af[mq][0], bf[0][nn][0], acc[4 + mq][nn]);
        acc[4 + mq][nn] = MFMA16(af[mq][1], bf[0][nn][1], acc[4 + mq][nn]);
      }
    __builtin_amdgcn_s_setprio(0);
    __builtin_amdgcn_s_barrier();

    // ---- phase 4: (mh1,nh1); stage B-h1(t+2); counted vmcnt
    STG_B(p * 2 + 1, oB10, oB11, kn2);
    asm volatile("s_waitcnt vmcnt(6)" ::: "memory");
    __builtin_amdgcn_s_barrier();
    __builtin_amdgcn_s_setprio(1);
#pragma unroll
    for (int mq = 0; mq < 4; ++mq)
#pragma unroll
      for (int nn = 0; nn < 2; ++nn) {
        acc[4 + mq][2 + nn] = MFMA16(af[mq][0], bf[1][nn][0], acc[4 + mq][2 + nn]);
        acc[4 + mq][2 + nn] = MFMA16(af[mq][1], bf[1][nn][1], acc[4 + mq][2 + nn]);
      }
    __builtin_amdgcn_s_setprio(0);
    __builtin_amdgcn_s_barrier();
  }
  asm volatile("s_waitcnt vmcnt(0)" ::: "memory");
#undef STG_A
#undef STG_B

  // ---- epilogue ----
#pragma unroll
  for (int m = 0; m < 8; ++m) {
    int row = bm + (m >> 2) * 128 + wr * 64 + (m & 3) * 16 + kg * 4;
#pragma unroll
    for (int n = 0; n < 4; ++n) {
      int col = bn + wc * 64 + n * 16 + lr;
      float bsv = (EPI == 3) ? 0.f : bias[col];
#pragma unroll
      for (int r = 0; r < 4; ++r) {
        if (row + r < M) {
          float v = acc[m][n][r] + bsv;
          if (EPI == 1) v = gelu_f(v);
          if (EPI == 2) Cf[(long)(row + r) * N + col] = v;
          else Cb[(long)(row + r) * N + col] = f2b(v);
        }
      }
    }
  }
}

// ---------- 8-key local attention ----------
__global__ __launch_bounds__(256) void attn_k(const u16* __restrict__ QH,
                                              const u16* __restrict__ KH,
                                              const u16* __restrict__ VH,
                                              u16* __restrict__ O) {
  int qr = blockIdx.x;
  int wgi = qr & 15;
  int hgi = (qr >> 4) % 20;
  int dgi = qr / 320;
  int c0 = (threadIdx.x >> 5) * 128 + (threadIdx.x & 31) * 4;
  ushort4 qv = *(const ushort4*)&QH[(long)qr * 1024 + c0];
  float q0 = b2f(qv.x), q1 = b2f(qv.y), q2 = b2f(qv.z), q3 = b2f(qv.w);
  long trs[8];
  float sc[8];
#pragma unroll
  for (int j = 0; j < 8; ++j) {
    int tr = ((2 * dgi + (j >> 2)) * 40 + (2 * hgi + ((j >> 1) & 1))) * 32 +
             (2 * wgi + (j & 1));
    trs[j] = (long)tr * 1024 + c0;
    ushort4 kv = *(const ushort4*)&KH[trs[j]];
    float p = q0 * b2f(kv.x) + q1 * b2f(kv.y) + q2 * b2f(kv.z) + q3 * b2f(kv.w);
    p += __shfl_xor(p, 16); p += __shfl_xor(p, 8); p += __shfl_xor(p, 4);
    p += __shfl_xor(p, 2);  p += __shfl_xor(p, 1);
    sc[j] = p * 0.088388347648318447f;  // 1/sqrt(128)
  }
  float mx = sc[0];
#pragma unroll
  for (int j = 1; j < 8; ++j) mx = fmaxf(mx, sc[j]);
  float ssum = 0.f;
#pragma unroll
  for (int j = 0; j < 8; ++j) { sc[j] = expf(sc[j] - mx); ssum += sc[j]; }
  float inv = 1.0f / ssum;
  float o0 = 0, o1 = 0, o2 = 0, o3 = 0;
#pragma unroll
  for (int j = 0; j < 8; ++j) {
    ushort4 vv = *(const ushort4*)&VH[trs[j]];
    float p = sc[j] * inv;
    o0 += p * b2f(vv.x); o1 += p * b2f(vv.y);
    o2 += p * b2f(vv.z); o3 += p * b2f(vv.w);
  }
  ushort4 ov; ov.x = f2b(o0); ov.y = f2b(o1); ov.z = f2b(o2); ov.w = f2b(o3);
  *(ushort4*)&O[(long)qr * 1024 + c0] = ov;
}

// ---------- host ----------
extern "C" void kernel_launch(void* const* d_in, const int* in_sizes, int n_in,
                              void* d_out, int out_size, void* d_ws,
                              size_t ws_size, hipStream_t stream) {
  const float* x      = (const float*)d_in[0];
  const float* q_w    = (const float*)d_in[1];
  const float* k_w1   = (const float*)d_in[2];
  const float* k_b1   = (const float*)d_in[3];
  const float* k_w2   = (const float*)d_in[4];
  const float* k_b2   = (const float*)d_in[5];
  const float* v_w1   = (const float*)d_in[6];
  const float* v_b1   = (const float*)d_in[7];
  const float* v_w2   = (const float*)d_in[8];
  const float* v_b2   = (const float*)d_in[9];
  const float* lnq_w  = (const float*)d_in[10];
  const float* lnq_b  = (const float*)d_in[11];
  const float* lnk_w  = (const float*)d_in[12];
  const float* lnk_b  = (const float*)d_in[13];
  const float* lnv_w  = (const float*)d_in[14];
  const float* lnv_b  = (const float*)d_in[15];
  const float* in_w   = (const float*)d_in[16];
  const float* in_b   = (const float*)d_in[17];
  const float* out_w  = (const float*)d_in[18];
  const float* out_b  = (const float*)d_in[19];
  const float* mlp_w1 = (const float*)d_in[20];
  const float* mlp_b1 = (const float*)d_in[21];
  const float* mlp_w2 = (const float*)d_in[22];
  const float* mlp_b2 = (const float*)d_in[23];
  float* out = (float*)d_out;

  // allow 128KB dynamic LDS on the GEMM instantiations (idempotent)
  hipFuncSetAttribute((const void*)gemm256<0>, hipFuncAttributeMaxDynamicSharedMemorySize, 131072);
  hipFuncSetAttribute((const void*)gemm256<1>, hipFuncAttributeMaxDynamicSharedMemorySize, 131072);
  hipFuncSetAttribute((const void*)gemm256<2>, hipFuncAttributeMaxDynamicSharedMemorySize, 131072);
  hipFuncSetAttribute((const void*)gemm256<3>, hipFuncAttributeMaxDynamicSharedMemorySize, 131072);

  char* base = (char*)d_ws;
  size_t off = 0;
  auto alloc_us = [&](size_t elems) -> u16* {
    u16* r = (u16*)(base + off);
    off += ((elems * 2 + 255) & ~(size_t)255);
    return r;
  };
  const size_t CC = 1024 * 1024;
  u16* wb_q   = alloc_us(CC);
  u16* wb_kv1 = alloc_us(2 * CC);
  u16* wb_k2  = alloc_us(CC);
  u16* wb_v2  = alloc_us(CC);
  u16* wb_in  = alloc_us(3 * CC);
  u16* wb_out = alloc_us(CC);
  u16* wb_m1  = alloc_us(2 * CC);
  u16* wb_m2  = alloc_us(4 * CC);
  float* b_kv1 = (float*)(base + off); off += 2048 * 4;

  auto cvt = [&](const float* s, u16* d, size_t n) {
    int n4 = (int)(n / 4);
    cvt_w<<<(n4 + 255) / 256, 256, 0, stream>>>(s, d, n4);
  };
  cvt(q_w, wb_q, CC);
  cvt(k_w1, wb_kv1, CC);        cvt(v_w1, wb_kv1 + CC, CC);
  cvt(k_w2, wb_k2, CC);         cvt(v_w2, wb_v2, CC);
  cvt(in_w, wb_in, 3 * CC);     cvt(out_w, wb_out, CC);
  cvt(mlp_w1, wb_m1, 2 * CC);   cvt(mlp_w2, wb_m2, 4 * CC);
  cat_bias<<<4, 256, 0, stream>>>(k_b1, v_b1, b_kv1);

  int s = 16;
  for (int cand = 1; cand <= 16; cand <<= 1) {
    size_t Tc_ = 40960ull / cand;
    size_t need = off + Tc_ * 11520ull + (1ull << 20);
    if (need <= ws_size) { s = cand; break; }
  }
  const int dcount = 32 / s;
  const int dgc = dcount / 2;
  const int Tc = dcount * 1280;
  const int Tq = dgc * 320;

  u16* Xb  = alloc_us((size_t)Tc * 1024);
  u16* Hb2 = alloc_us((size_t)Tc * 2048);
  u16* Kb  = alloc_us((size_t)Tc * 1024);
  u16* Vb  = alloc_us((size_t)Tc * 1024);
  u16* Qp  = alloc_us((size_t)Tq * 1024);
  u16* QQ  = alloc_us((size_t)Tq * 1024);
  u16* QHb = alloc_us((size_t)Tq * 1024);
  u16* Ob  = alloc_us((size_t)Tq * 1024);
  u16* O2  = alloc_us((size_t)Tq * 1024);
  u16* Hm  = Kb;

  auto launch_gemm = [&](int EPI, const u16* A, const u16* B, const float* bias,
                         float* Cf, u16* Cb, int M, int N, int K, int lda) {
    int nbx = (M + 255) / 256, nby = N / 256;
    dim3 g(nbx * nby);
    switch (EPI) {
      case 0: gemm256<0><<<g, 512, 131072, stream>>>(A, B, bias, Cf, Cb, M, N, K, lda, nbx, nby); break;
      case 1: gemm256<1><<<g, 512, 131072, stream>>>(A, B, bias, Cf, Cb, M, N, K, lda, nbx, nby); break;
      case 2: gemm256<2><<<g, 512, 131072, stream>>>(A, B, bias, Cf, Cb, M, N, K, lda, nbx, nby); break;
      default: gemm256<3><<<g, 512, 131072, stream>>>(A, B, bias, Cf, Cb, M, N, K, lda, nbx, nby); break;
    }
  };

  for (int n = 0; n < 2; ++n) {
    for (int sl = 0; sl < s; ++sl) {
      long tok0 = (long)n * 40960 + (long)sl * dcount * 1280;
      long q0g  = (long)n * 5120 + (long)sl * dgc * 320;
      const float* xg = x + tok0 * 1024;

      pool_cvt<<<Tq, 256, 0, stream>>>(xg, Xb, Qp);

      launch_gemm(1, Xb, wb_kv1, b_kv1, nullptr, Hb2, Tc, 2048, 1024, 1024);
      launch_gemm(0, Hb2, wb_k2, k_b2, nullptr, Kb, Tc, 1024, 1024, 2048);
      ln_ip<<<Tc, 256, 0, stream>>>(Kb, lnk_w, lnk_b);
      launch_gemm(0, Hb2 + 1024, wb_v2, v_b2, nullptr, Vb, Tc, 1024, 1024, 2048);
      ln_ip<<<Tc, 256, 0, stream>>>(Vb, lnv_w, lnv_b);

      launch_gemm(3, Qp, wb_q, nullptr, nullptr, QQ, Tq, 1024, 1024, 1024);
      ln_ip<<<Tq, 256, 0, stream>>>(QQ, lnq_w, lnq_b);
      launch_gemm(0, QQ, wb_in, in_b, nullptr, QHb, Tq, 1024, 1024, 1024);

      launch_gemm(0, Kb, wb_in + CC, in_b + 1024, nullptr, Xb, Tc, 1024, 1024, 1024);
      launch_gemm(0, Vb, wb_in + 2 * CC, in_b + 2048, nullptr, Hb2, Tc, 1024, 1024, 1024);

      attn_k<<<Tq, 256, 0, stream>>>(QHb, Xb, Hb2, Ob);

      launch_gemm(0, Ob, wb_out, out_b, nullptr, O2, Tq, 1024, 1024, 1024);
      launch_gemm(1, O2, wb_m1, mlp_b1, nullptr, Hm, Tq, 2048, 1024, 1024);
      launch_gemm(2, Hm, wb_m2, mlp_b2, out + q0g * 2048, nullptr, Tq, 2048, 2048, 2048);
    }
  }
}